// Round 4
// baseline (298.170 us; speedup 1.0000x reference)
//
#include <hip/hip_runtime.h>

// LargeEmbedding: out[i, :] = pages_flat[indices[i], :]
// pages: [8, 125000, 64] f32 stacked contiguously; page_id*125000+row_id == idx,
// so this is a flat row gather of 256 B rows. Pure memory-bound.
//
// R4 = R3 with 4 independent 16 B NT loads per thread (was 2):
//  - 2048 blocks x 256 thr = 8192 waves = full 32 waves/CU occupancy.
//  - 4 outstanding gathers/thread to saturate HBM latency-BW product.
// Kernel device time is already ~15-30 us vs ~280 us fixed harness overhead
// (1 GB ws poison + 244 MB input restore dominate dur_us); this is the last
// latency-hiding lever.

typedef float f32x4 __attribute__((ext_vector_type(4)));

__global__ __launch_bounds__(256) void LargeEmbedding_90494960927132_kernel(
    const int* __restrict__ indices,
    const f32x4* __restrict__ pages4,    // flat [1e6 * 16] x 16B
    f32x4* __restrict__ out4)
{
    const int nthreads = gridDim.x * 256;          // n4 / 4
    int g0 = blockIdx.x * 256 + threadIdx.x;
    int g1 = g0 + nthreads;
    int g2 = g1 + nthreads;
    int g3 = g2 + nthreads;

    int idx0 = indices[g0 >> 4];                   // 16-lane broadcast, L1 hit
    int idx1 = indices[g1 >> 4];
    int idx2 = indices[g2 >> 4];
    int idx3 = indices[g3 >> 4];

    f32x4 v0 = __builtin_nontemporal_load(&pages4[idx0 * 16 + (g0 & 15)]);
    f32x4 v1 = __builtin_nontemporal_load(&pages4[idx1 * 16 + (g1 & 15)]);
    f32x4 v2 = __builtin_nontemporal_load(&pages4[idx2 * 16 + (g2 & 15)]);
    f32x4 v3 = __builtin_nontemporal_load(&pages4[idx3 * 16 + (g3 & 15)]);
    __builtin_nontemporal_store(v0, &out4[g0]);
    __builtin_nontemporal_store(v1, &out4[g1]);
    __builtin_nontemporal_store(v2, &out4[g2]);
    __builtin_nontemporal_store(v3, &out4[g3]);
}

extern "C" void kernel_launch(void* const* d_in, const int* in_sizes, int n_in,
                              void* d_out, int out_size, void* d_ws, size_t ws_size,
                              hipStream_t stream) {
    const int* indices  = (const int*)d_in[0];      // [16*8192] int32
    const f32x4* pages4 = (const f32x4*)d_in[1];    // [8*125000*64] f32 as 16B vecs
    f32x4* out4         = (f32x4*)d_out;

    int n4 = out_size / 4;               // 2,097,152 float4
    int blocks = n4 / (256 * 4);         // 2048 blocks, 4 float4/thread, exact
    LargeEmbedding_90494960927132_kernel<<<blocks, 256, 0, stream>>>(
        indices, pages4, out4);
}